// Round 7
// baseline (18154.819 us; speedup 1.0000x reference)
//
#include <hip/hip_runtime.h>

// Persistent 3-layer tanh-RNN, B=32, S=1024, I=128, H=512.
// f16 split-2 (hi + lo*2^-12) x 3 MFMA products == fp32-class precision.
//
// Geometry rework (R7): 8 blocks x 512 threads per layer (24 blocks total).
// Each block owns 64 output cols x all 32 batches; 8 waves = 4 col-tiles x
// 2 K-halves; each wave computes BOTH 16-row tiles for its (col-tile,K-half).
//   - split-K is 2-way (was 4-way): one small LDS reduce, epilogue runs on
//     4 waves in parallel (was 1 serial wave);
//   - wave 7 is a dedicated poller: polls next step's flags WHILE the
//     epilogue waves store (poll overlaps the producer tail);
//   - per-wave release bytes (4 bytes = 1 flag dword per block-step): no
//     producer-side barrier between stores and flag;
//   - no self-flag check (own sc1 stores are drained before the release
//     byte; the post-poll acquire fence makes them load-visible);
//   - producers per layer 32 -> 8: less max-of-N jitter, half the
//     redundant h-row refetch.
// Sync primitives are byte-for-byte the proven R2/R6 ones: ballot poll of
// agent-scope flags, acquire fence, plain cached data loads, sc1 agent data
// stores, release byte store. No placement assumptions (R3/R4 lesson), no
// agent atomic data loads (R5 lesson). All polls timeout-bounded.

typedef _Float16 half8 __attribute__((ext_vector_type(8)));
typedef float f32x4 __attribute__((ext_vector_type(4)));
typedef unsigned int uint32;
typedef unsigned short ushort16;

#define SCOPE_AGENT __HIP_MEMORY_SCOPE_AGENT
#define PLANE_ELEMS (32 * 1024 * 512)
#define FLAG_BYTES (3 * 8 * 1024 * 4)  // [l][jg8][t] dwords (4 bytes = 4 epilogue waves) = 96 KB

__device__ __forceinline__ half8 h8(uint32 a, uint32 b, uint32 c, uint32 d) {
  union { uint32 u[4]; half8 h; } x;
  x.u[0] = a; x.u[1] = b; x.u[2] = c; x.u[3] = d;
  return x.h;
}

// pair dword: low16 = hi-f16 bits, high16 = lo-f16 bits
__device__ __forceinline__ void unpack_pair8(uint4 a, uint4 b, half8& hi, half8& lo) {
  hi = h8((a.x & 0xFFFFu) | (a.y << 16),
          (a.z & 0xFFFFu) | (a.w << 16),
          (b.x & 0xFFFFu) | (b.y << 16),
          (b.z & 0xFFFFu) | (b.w << 16));
  lo = h8((a.x >> 16) | (a.y & 0xFFFF0000u),
          (a.z >> 16) | (a.w & 0xFFFF0000u),
          (b.x >> 16) | (b.y & 0xFFFF0000u),
          (b.z >> 16) | (b.w & 0xFFFF0000u));
}

__device__ __forceinline__ void split8f(const float* v, half8& hi, half8& lo) {
  union { _Float16 e[8]; half8 h; } H, L;
#pragma unroll
  for (int i = 0; i < 8; ++i) {
    _Float16 h = (_Float16)v[i];
    H.e[i] = h;
    L.e[i] = (_Float16)((v[i] - (float)h) * 4096.0f);  // exact residual, scaled into f16 normal range
  }
  hi = H.h; lo = L.h;
}

__device__ __forceinline__ uint32 pack_pair(float xx) {
  _Float16 h = (_Float16)xx;
  _Float16 l = (_Float16)((xx - (float)h) * 4096.0f);
  union { _Float16 f; ushort16 u; } ch, cl;
  ch.f = h; cl.f = l;
  return (uint32)ch.u | ((uint32)cl.u << 16);
}

__device__ __forceinline__ void frag_from_f32(const float* p, half8& hi, half8& lo) {
  float v[8];
  *(float4*)(v)     = *(const float4*)(p);
  *(float4*)(v + 4) = *(const float4*)(p + 4);
  split8f(v, hi, lo);
}

__device__ __forceinline__ void frag_from_pairs(const uint32* p, half8& hi, half8& lo) {
  uint4 a = *(const uint4*)p;
  uint4 b = *(const uint4*)(p + 4);
  unpack_pair8(a, b, hi, lo);
}

template <int L>
__device__ void run_layer(const float* __restrict__ x, const float* __restrict__ h0,
                          const float* __restrict__ w_ih0, const float* __restrict__ w_ihs,
                          const float* __restrict__ w_hhs, const float* __restrict__ b_ihs,
                          const float* __restrict__ b_hhs, uint32* __restrict__ plane0,
                          uint32* __restrict__ plane1, float* __restrict__ outp, int jg) {
  constexpr int NT = (L == 0) ? 10 : 16;    // K-tiles (of 32) per wave: L0 = 4 in + 16 rec over 2 halves
  constexpr int INKT = (L == 0) ? 4 : 16;   // global tile index g < INKT -> input half, else recurrent

  unsigned char* flagb = (unsigned char*)outp;  // [l][jg8][t] flag dwords, byte wc per epilogue wave
  uint32* flag32 = (uint32*)outp;
  float* hidden = outp;
  float* out2 = outp + 3 * 32 * 512;

  const int tid = threadIdx.x;
  const int w = tid >> 6;                   // 0..7
  const int lane = tid & 63;
  const int ln16 = lane & 15;
  const int kgrp = lane >> 4;               // frag k-group: k8 = kgrp*8
  const int wc = w & 3;                     // col-tile 0..3
  const int kh = w >> 2;                    // K-half 0/1
  const int j = jg * 64 + wc * 16 + ln16;   // this lane's output column (B-frag col)
  const int r0 = ln16;                      // A row-tile 0 batch row
  const int r1 = 16 + ln16;                 // A row-tile 1 batch row

  __shared__ f32x4 red[4 * 2 * 64];         // [wc][P0/P1][lane] from kh=1 waves
  __shared__ int s_abort;
  if (tid == 0) s_abort = 0;

  // ---- preload weights (step-invariant) into VGPRs as hi/lo B-frags ----
  half8 Bh[NT], Bl[NT];
#pragma unroll
  for (int i = 0; i < NT; ++i) {
    const int g = kh * NT + i;
    const float* wp;
    if (L == 0) {
      if (g < 4) wp = w_ih0 + j * 128 + g * 32 + kgrp * 8;
      else       wp = w_hhs + j * 512 + (g - 4) * 32 + kgrp * 8;
    } else {
      if (g < 16) wp = w_ihs + (L - 1) * 512 * 512 + j * 512 + g * 32 + kgrp * 8;
      else        wp = w_hhs + L * 512 * 512 + j * 512 + (g - 16) * 32 + kgrp * 8;
    }
    frag_from_f32(wp, Bh[i], Bl[i]);
  }

  const float bias = b_ihs[L * 512 + j] + b_hhs[L * 512 + j];  // P0 and P1 share the column
  uint32* myplane = (L == 0) ? plane0 : plane1;                // L==2 never uses it
  const uint32* plane_in = (L == 1) ? plane0 : plane1;         // L==2 reads plane1; L==0 unused
  __syncthreads();

  for (int t = 0; t < 1024; ++t) {
    // ---- poller wave 7: own-layer OTHER blocks (t-1) + upstream (t), fused ballot ----
    if (w == 7) {
      const uint32* pp = nullptr;
      if (lane < 7) {
        if (t > 0) { const int jo = lane + (lane >= jg ? 1 : 0);
                     pp = flag32 + (L * 8 + jo) * 1024 + (t - 1); }
      } else if (lane >= 8 && lane < 16) {
        if (L > 0) pp = flag32 + ((L - 1) * 8 + (lane - 8)) * 1024 + t;
      }
      int spins = 0;
      for (;;) {
        bool ready = true;
        if (pp) ready = (__hip_atomic_load(pp, __ATOMIC_RELAXED, SCOPE_AGENT) == 0x01010101u);
        if (__ballot(ready) == ~0ull) break;
        if (++spins > 250000) { if (lane == 0) s_abort = 1; break; }  // bounded -> degrade, never hang
        if (spins > 64) __builtin_amdgcn_s_sleep(1);
      }
      __builtin_amdgcn_fence(__ATOMIC_ACQUIRE, "agent");  // invalidate stale L1/L2 lines
    }
    __syncthreads();
    if (s_abort) break;

    // ---- per-step row bases ----
    const uint32* inPt  = (L == 0) ? nullptr : plane_in + t * 32 * 512;        // input rows (pairs)
    const uint32* recPt = (L == 2 || t == 0) ? nullptr : myplane + (t - 1) * 32 * 512;  // rec rows (pairs)

    f32x4 C0 = {0.f, 0.f, 0.f, 0.f}, C1 = C0, X0 = C0, X1 = C0;

#pragma unroll
    for (int i = 0; i < NT; ++i) {
      const int g = kh * NT + i;
      half8 A0h, A0l, A1h, A1l;
      if (g < INKT) {  // input half
        const int k = g * 32 + kgrp * 8;
        if (L == 0) {
          frag_from_f32(x + (r0 * 1024 + t) * 128 + k, A0h, A0l);
          frag_from_f32(x + (r1 * 1024 + t) * 128 + k, A1h, A1l);
        } else {
          frag_from_pairs(inPt + r0 * 512 + k, A0h, A0l);
          frag_from_pairs(inPt + r1 * 512 + k, A1h, A1l);
        }
      } else {         // recurrent half
        const int k = (g - INKT) * 32 + kgrp * 8;
        if (t == 0) {
          frag_from_f32(h0 + (L * 32 + r0) * 512 + k, A0h, A0l);
          frag_from_f32(h0 + (L * 32 + r1) * 512 + k, A1h, A1l);
        } else if (L == 2) {
          frag_from_f32(out2 + (r0 * 1024 + (t - 1)) * 512 + k, A0h, A0l);
          frag_from_f32(out2 + (r1 * 1024 + (t - 1)) * 512 + k, A1h, A1l);
        } else {
          frag_from_pairs(recPt + r0 * 512 + k, A0h, A0l);
          frag_from_pairs(recPt + r1 * 512 + k, A1h, A1l);
        }
      }
      C0 = __builtin_amdgcn_mfma_f32_16x16x32_f16(A0h, Bh[i], C0, 0, 0, 0);
      C1 = __builtin_amdgcn_mfma_f32_16x16x32_f16(A1h, Bh[i], C1, 0, 0, 0);
      X0 = __builtin_amdgcn_mfma_f32_16x16x32_f16(A0h, Bl[i], X0, 0, 0, 0);
      X1 = __builtin_amdgcn_mfma_f32_16x16x32_f16(A1h, Bl[i], X1, 0, 0, 0);
      X0 = __builtin_amdgcn_mfma_f32_16x16x32_f16(A0l, Bh[i], X0, 0, 0, 0);
      X1 = __builtin_amdgcn_mfma_f32_16x16x32_f16(A1l, Bh[i], X1, 0, 0, 0);
    }

    f32x4 P0 = C0 + X0 * (1.0f / 4096.0f);
    f32x4 P1 = C1 + X1 * (1.0f / 4096.0f);

    if (kh == 1) {
      red[(wc * 2 + 0) * 64 + lane] = P0;
      red[(wc * 2 + 1) * 64 + lane] = P1;
    }
    __syncthreads();

    if (kh == 0) {
      P0 += red[(wc * 2 + 0) * 64 + lane];
      P1 += red[(wc * 2 + 1) * 64 + lane];
      const int brow = kgrp * 4;  // C/D: col=lane&15, row=(lane>>4)*4+r ; P1 rows +16
#pragma unroll
      for (int r = 0; r < 4; ++r) {
        const float y0 = tanhf(P0[r] + bias);
        const float y1 = tanhf(P1[r] + bias);
        const int b0 = brow + r;
        const int b1 = 16 + brow + r;
        if (L < 2) {
          __hip_atomic_store(&myplane[(t * 32 + b0) * 512 + j], pack_pair(y0), __ATOMIC_RELAXED, SCOPE_AGENT);
          __hip_atomic_store(&myplane[(t * 32 + b1) * 512 + j], pack_pair(y1), __ATOMIC_RELAXED, SCOPE_AGENT);
        } else {
          __hip_atomic_store(&out2[(b0 * 1024 + t) * 512 + j], y0, __ATOMIC_RELAXED, SCOPE_AGENT);
          __hip_atomic_store(&out2[(b1 * 1024 + t) * 512 + j], y1, __ATOMIC_RELAXED, SCOPE_AGENT);
          if (t == 1023) {
            hidden[2 * 32 * 512 + b0 * 512 + j] = y0;
            hidden[2 * 32 * 512 + b1 * 512 + j] = y1;
          }
        }
      }
      // per-WAVE release byte (orders this wave's stores only; 4 bytes -> full dword)
      if (lane == 0)
        __hip_atomic_store(flagb + ((L * 8 + jg) * 1024 + t) * 4 + wc,
                           (unsigned char)1, __ATOMIC_RELEASE, SCOPE_AGENT);
    }
  }
}

__global__ __launch_bounds__(512) void rnn_persist(
    const float* __restrict__ x, const float* __restrict__ h0,
    const float* __restrict__ w_ih0, const float* __restrict__ w_ihs,
    const float* __restrict__ w_hhs, const float* __restrict__ b_ihs,
    const float* __restrict__ b_hhs, uint32* __restrict__ plane0,
    uint32* __restrict__ plane1, float* __restrict__ outp) {
  const int bid = blockIdx.x;
  const int l = bid >> 3;          // 0..2
  const int jg = bid & 7;          // 0..7 (64 cols each)
  if (l == 0)      run_layer<0>(x, h0, w_ih0, w_ihs, w_hhs, b_ihs, b_hhs, plane0, plane1, outp, jg);
  else if (l == 1) run_layer<1>(x, h0, w_ih0, w_ihs, w_hhs, b_ihs, b_hhs, plane0, plane1, outp, jg);
  else             run_layer<2>(x, h0, w_ih0, w_ihs, w_hhs, b_ihs, b_hhs, plane0, plane1, outp, jg);
}

// hidden[l][b][j] for l in {0,1} from the last pair-plane slot (exact-ish: hi + lo*2^-12)
__global__ __launch_bounds__(256) void finals_kernel(const uint32* __restrict__ plane0,
                                                     const uint32* __restrict__ plane1,
                                                     float* __restrict__ outp) {
  int i = blockIdx.x * 256 + threadIdx.x;
  if (i >= 2 * 32 * 512) return;
  int l = i >> 14;
  int r = i & 16383;  // b*512 + j
  const uint32* pl = l ? plane1 : plane0;
  uint32 p = pl[1023 * 32 * 512 + r];
  union { ushort16 u; _Float16 f; } h, lo;
  h.u = (ushort16)(p & 0xFFFFu);
  lo.u = (ushort16)(p >> 16);
  outp[i] = (float)h.f + (float)lo.f * (1.0f / 4096.0f);
}

extern "C" void kernel_launch(void* const* d_in, const int* in_sizes, int n_in,
                              void* d_out, int out_size, void* d_ws, size_t ws_size,
                              hipStream_t stream) {
  const float* x     = (const float*)d_in[0];
  const float* h0    = (const float*)d_in[1];
  const float* w_ih0 = (const float*)d_in[2];
  const float* w_ihs = (const float*)d_in[3];
  const float* w_hhs = (const float*)d_in[4];
  const float* b_ihs = (const float*)d_in[5];
  const float* b_hhs = (const float*)d_in[6];

  uint32* plane0 = (uint32*)d_ws;            // layer-0 outputs, (hi,lo) f16 pairs, 64 MB
  uint32* plane1 = plane0 + PLANE_ELEMS;     // layer-1 outputs, 64 MB

  // zero the flag dwords (dead hidden region of d_out, below hidden[2] at
  // 128 KB; rewritten by finals_kernel at the end)
  hipMemsetAsync(d_out, 0, FLAG_BYTES, stream);
  rnn_persist<<<24, 512, 0, stream>>>(x, h0, w_ih0, w_ihs, w_hhs, b_ihs, b_hhs,
                                      plane0, plane1, (float*)d_out);
  finals_kernel<<<128, 256, 0, stream>>>(plane0, plane1, (float*)d_out);
}

// Round 8
// 7903.554 us; speedup vs baseline: 2.2970x; 2.2970x over previous
//
#include <hip/hip_runtime.h>

// Persistent 3-layer tanh-RNN, B=32, S=1024, I=128, H=512.
// f16 split-2 (hi + lo*2^-12) x 3 MFMA products == fp32-class precision.
// 96 blocks = 3 layers x 16 j-groups(32 j) x 2 b-groups(16 b); weights live in
// VGPRs as MFMA B-frags for the whole kernel (R6 geometry, best verified).
//
// R8: FLAG-FREE sync — self-validating data. R6's 6.5us/step chain was
// data-drain -> flag-release -> flag-poll -> fence -> L3 data re-read, i.e.
// readiness and data travel separately (3 extra fabric hops). Now every
// stored dword carries a validity tag:
//   - pair planes: bit16 (LSB of lo-f16) forced to 1 -> h error ~2^-22;
//     slots are write-once and planes are zeroed at launch, so bit16=0
//     means "not yet written". No epochs, no aliasing.
//   - out2 f32 (L2 rec source AND final output): bit0 forced to 1 (~6e-8).
// Consumers load mutable A-tiles with agent-scope 8B atomic loads (the
// primitive R5 PROVED correct) and retry until all tags set. Producers:
// relaxed agent stores only — no drain, no release, no flag. Consumers:
// no flag poll, no acquire fence — x/h0/weights stay plain and cached.
// Per-wave polling gates each wave only on the producers of its own K-slice.
// Bounded retries + LDS abort: degrade, never hang. Planes+out2 are memset
// per launch (tag freshness / re-poison safety).

typedef _Float16 half8 __attribute__((ext_vector_type(8)));
typedef float f32x4 __attribute__((ext_vector_type(4)));
typedef unsigned int uint32;
typedef unsigned long long uint64;
typedef unsigned short ushort16;

#define SCOPE_AGENT __HIP_MEMORY_SCOPE_AGENT
#define SCOPE_WG __HIP_MEMORY_SCOPE_WORKGROUP
#define PLANE_ELEMS (32 * 1024 * 512)

__device__ __forceinline__ half8 h8(uint32 a, uint32 b, uint32 c, uint32 d) {
  union { uint32 u[4]; half8 h; } x;
  x.u[0] = a; x.u[1] = b; x.u[2] = c; x.u[3] = d;
  return x.h;
}

// pair dword: low16 = hi-f16 bits, high16 = lo-f16 bits (bit16 = tag)
__device__ __forceinline__ void unpack_pair8(uint4 a, uint4 b, half8& hi, half8& lo) {
  hi = h8((a.x & 0xFFFFu) | (a.y << 16),
          (a.z & 0xFFFFu) | (a.w << 16),
          (b.x & 0xFFFFu) | (b.y << 16),
          (b.z & 0xFFFFu) | (b.w << 16));
  lo = h8((a.x >> 16) | (a.y & 0xFFFF0000u),
          (a.z >> 16) | (a.w & 0xFFFF0000u),
          (b.x >> 16) | (b.y & 0xFFFF0000u),
          (b.z >> 16) | (b.w & 0xFFFF0000u));
}

__device__ __forceinline__ void split8f(const float* v, half8& hi, half8& lo) {
  union { _Float16 e[8]; half8 h; } H, L;
#pragma unroll
  for (int i = 0; i < 8; ++i) {
    _Float16 h = (_Float16)v[i];
    H.e[i] = h;
    L.e[i] = (_Float16)((v[i] - (float)h) * 4096.0f);  // exact residual, scaled into f16 normal range
  }
  hi = H.h; lo = L.h;
}

__device__ __forceinline__ uint32 pack_pair(float xx) {
  _Float16 h = (_Float16)xx;
  _Float16 l = (_Float16)((xx - (float)h) * 4096.0f);
  union { _Float16 f; ushort16 u; } ch, cl;
  ch.f = h; cl.f = l;
  return (uint32)ch.u | ((uint32)cl.u << 16);
}

__device__ __forceinline__ void frag_from_f32(const float* p, half8& hi, half8& lo) {
  float v[8];
  *(float4*)(v)     = *(const float4*)(p);
  *(float4*)(v + 4) = *(const float4*)(p + 4);
  split8f(v, hi, lo);
}

// 32B agent-coherent load (4 x 8B atomic, R5-proven primitive) + AND of qwords
__device__ __forceinline__ void ld32_agent(const void* p, uint4& a, uint4& b, uint64& andq) {
  const uint64* q = (const uint64*)p;
  uint64 q0 = __hip_atomic_load(q + 0, __ATOMIC_RELAXED, SCOPE_AGENT);
  uint64 q1 = __hip_atomic_load(q + 1, __ATOMIC_RELAXED, SCOPE_AGENT);
  uint64 q2 = __hip_atomic_load(q + 2, __ATOMIC_RELAXED, SCOPE_AGENT);
  uint64 q3 = __hip_atomic_load(q + 3, __ATOMIC_RELAXED, SCOPE_AGENT);
  union { uint64 qq[2]; uint4 v; } A, B;
  A.qq[0] = q0; A.qq[1] = q1; B.qq[0] = q2; B.qq[1] = q3;
  a = A.v; b = B.v;
  andq = q0 & q1 & q2 & q3;
}

template <int L>
__device__ void run_layer(const float* __restrict__ x, const float* __restrict__ h0,
                          const float* __restrict__ w_ih0, const float* __restrict__ w_ihs,
                          const float* __restrict__ w_hhs, const float* __restrict__ b_ihs,
                          const float* __restrict__ b_hhs, uint32* __restrict__ plane0,
                          uint32* __restrict__ plane1, float* __restrict__ outp, int jg, int bg) {
  constexpr int NKT = (L == 0) ? 20 : 32;   // K-tiles of 32 (l0: 4 x-tiles + 16 rec; else 16 in + 16 rec)
  constexpr int KTN = NKT / 4;              // tiles per wave
  constexpr int RECKT = (L == 0) ? 4 : 16;  // first recurrent tile

  float* hidden = outp;
  float* out2 = outp + 3 * 32 * 512;

  const int tid = threadIdx.x;
  const int w = tid >> 6;
  const int lane = tid & 63;
  const int ln16 = lane & 15;
  const int kgrp = lane >> 4;               // frag k-group: k8 = kgrp*8
  const int j0 = jg * 32;
  const int jc0 = j0 + ln16;                // jtile-0 column for this lane
  const int jc1 = j0 + 16 + ln16;           // jtile-1 column
  const int bloc = bg * 16 + ln16;          // A-frag row (batch)
  const int ktb = w * KTN;

  __shared__ f32x4 red[3 * 2 * 64];
  __shared__ int s_abort;
  if (tid == 0) s_abort = 0;

  // ---- preload weights (step-invariant) into VGPRs as hi/lo B-frags ----
  half8 Bhi[2][KTN], Blo[2][KTN];
#pragma unroll
  for (int jt = 0; jt < 2; ++jt) {
    const int j = j0 + jt * 16 + ln16;
#pragma unroll
    for (int ktl = 0; ktl < KTN; ++ktl) {
      const int kt = ktb + ktl;
      const float* wp;
      if (L == 0) {
        if (kt < 4) wp = w_ih0 + j * 128 + kt * 32 + kgrp * 8;
        else        wp = w_hhs + j * 512 + (kt - 4) * 32 + kgrp * 8;
      } else {
        if (kt < 16) wp = w_ihs + (L - 1) * 512 * 512 + j * 512 + kt * 32 + kgrp * 8;
        else         wp = w_hhs + L * 512 * 512 + j * 512 + (kt - 16) * 32 + kgrp * 8;
      }
      frag_from_f32(wp, Bhi[jt][ktl], Blo[jt][ktl]);
    }
  }

  const float bias0 = b_ihs[L * 512 + jc0] + b_hhs[L * 512 + jc0];
  const float bias1 = b_ihs[L * 512 + jc1] + b_hhs[L * 512 + jc1];
  uint32* myplane = (L == 0) ? plane0 : plane1;  // L==2 never uses it
  __syncthreads();

  for (int t = 0; t < 1024; ++t) {
    // ---- per-step source row pointers ----
    const float* recF = nullptr; const uint32* recP = nullptr;
    if (t == 0)      recF = h0 + (L * 32 + bloc) * 512;
    else if (L < 2)  recP = myplane + ((t - 1) * 32 + bloc) * 512;
    else             recF = out2 + (bloc * 1024 + (t - 1)) * 512;

    const float* inF = nullptr; const uint32* inP = nullptr;
    if (L == 0)      inF = x + (bloc * 1024 + t) * 128;
    else if (L == 1) inP = plane0 + (t * 32 + bloc) * 512;
    else             inP = plane1 + (t * 32 + bloc) * 512;

    uint4 ra[KTN], rb[KTN];

    // ---- immutable tiles: plain cached loads, once ----
#pragma unroll
    for (int ktl = 0; ktl < KTN; ++ktl) {
      const int kt = ktb + ktl;
      if (kt < RECKT) {
        if (L == 0) {
          const int k = kt * 32 + kgrp * 8;
          ra[ktl] = *(const uint4*)(inF + k); rb[ktl] = *(const uint4*)(inF + k + 4);
        }
      } else if (t == 0) {
        const int k = (kt - RECKT) * 32 + kgrp * 8;
        ra[ktl] = *(const uint4*)(recF + k); rb[ktl] = *(const uint4*)(recF + k + 4);
      }
    }

    // ---- mutable tiles: poll the data itself (tag bits) until valid ----
    int spins = 0;
    for (;;) {
      bool lane_ok = true;
#pragma unroll
      for (int ktl = 0; ktl < KTN; ++ktl) {
        const int kt = ktb + ktl;
        uint64 aq;
        if (kt < RECKT) {
          if (L > 0) {  // cross-layer input pairs: tag = bit16 of every dword
            const int k = kt * 32 + kgrp * 8;
            ld32_agent(inP + k, ra[ktl], rb[ktl], aq);
            lane_ok = lane_ok && ((((aq >> 16) & (aq >> 48)) & 1ull) != 0ull);
          }
        } else if (t > 0) {
          const int k = (kt - RECKT) * 32 + kgrp * 8;
          if (L == 2) {  // rec from out2 f32: tag = bit0 of every dword
            ld32_agent(recF + k, ra[ktl], rb[ktl], aq);
            lane_ok = lane_ok && (((aq & (aq >> 32)) & 1ull) != 0ull);
          } else {       // rec pairs: tag = bit16
            ld32_agent(recP + k, ra[ktl], rb[ktl], aq);
            lane_ok = lane_ok && ((((aq >> 16) & (aq >> 48)) & 1ull) != 0ull);
          }
        }
      }
      if (__ballot(lane_ok) == ~0ull) break;
      if (++spins > 20000) {  // ~16ms budget; degrade, never hang
        __hip_atomic_store(&s_abort, 1, __ATOMIC_RELAXED, SCOPE_WG);
        break;
      }
    }

    // ---- decode + MFMA (R6 compute, fed from ra/rb) ----
    f32x4 C0 = {0.f, 0.f, 0.f, 0.f}, C1 = C0, X0 = C0, X1 = C0;
#pragma unroll
    for (int ktl = 0; ktl < KTN; ++ktl) {
      const int kt = ktb + ktl;
      const bool isf32 = (kt < RECKT) ? (L == 0) : (t == 0 || L == 2);
      half8 Ahi, Alo;
      if (isf32) {
        float v[8];
        *(uint4*)(v)     = ra[ktl];
        *(uint4*)(v + 4) = rb[ktl];
        split8f(v, Ahi, Alo);
      } else {
        unpack_pair8(ra[ktl], rb[ktl], Ahi, Alo);
      }
      C0 = __builtin_amdgcn_mfma_f32_16x16x32_f16(Ahi, Bhi[0][ktl], C0, 0, 0, 0);
      C1 = __builtin_amdgcn_mfma_f32_16x16x32_f16(Ahi, Bhi[1][ktl], C1, 0, 0, 0);
      X0 = __builtin_amdgcn_mfma_f32_16x16x32_f16(Ahi, Blo[0][ktl], X0, 0, 0, 0);
      X1 = __builtin_amdgcn_mfma_f32_16x16x32_f16(Ahi, Blo[1][ktl], X1, 0, 0, 0);
      X0 = __builtin_amdgcn_mfma_f32_16x16x32_f16(Alo, Bhi[0][ktl], X0, 0, 0, 0);
      X1 = __builtin_amdgcn_mfma_f32_16x16x32_f16(Alo, Bhi[1][ktl], X1, 0, 0, 0);
    }

    f32x4 P0 = C0 + X0 * (1.0f / 4096.0f);
    f32x4 P1 = C1 + X1 * (1.0f / 4096.0f);

    if (w > 0) {
      red[((w - 1) * 2 + 0) * 64 + lane] = P0;
      red[((w - 1) * 2 + 1) * 64 + lane] = P1;
    }
    __syncthreads();

    if (w == 0) {
#pragma unroll
      for (int wv = 0; wv < 3; ++wv) {
        P0 += red[(wv * 2 + 0) * 64 + lane];
        P1 += red[(wv * 2 + 1) * 64 + lane];
      }
      const int brow = bg * 16 + kgrp * 4;  // C/D: col=lane&15, row=(lane>>4)*4+r
#pragma unroll
      for (int r = 0; r < 4; ++r) {
        const float y0 = tanhf(P0[r] + bias0);
        const float y1 = tanhf(P1[r] + bias1);
        const int b = brow + r;
        if (L < 2) {
          // tagged pair stores: bit16 = written (lo-f16 LSB, error ~2^-22)
          __hip_atomic_store(&myplane[(t * 32 + b) * 512 + jc0], pack_pair(y0) | 0x10000u, __ATOMIC_RELAXED, SCOPE_AGENT);
          __hip_atomic_store(&myplane[(t * 32 + b) * 512 + jc1], pack_pair(y1) | 0x10000u, __ATOMIC_RELAXED, SCOPE_AGENT);
        } else {
          // tagged f32 stores: bit0 = written (~6e-8)
          __hip_atomic_store((uint32*)&out2[(b * 1024 + t) * 512 + jc0], __float_as_uint(y0) | 1u, __ATOMIC_RELAXED, SCOPE_AGENT);
          __hip_atomic_store((uint32*)&out2[(b * 1024 + t) * 512 + jc1], __float_as_uint(y1) | 1u, __ATOMIC_RELAXED, SCOPE_AGENT);
          if (t == 1023) {
            hidden[2 * 32 * 512 + b * 512 + jc0] = y0;
            hidden[2 * 32 * 512 + b * 512 + jc1] = y1;
          }
        }
      }
    }
    __syncthreads();  // red WAR protection for next step + s_abort visibility
    if (s_abort) break;
  }
}

__global__ __launch_bounds__(256) void rnn_persist(
    const float* __restrict__ x, const float* __restrict__ h0,
    const float* __restrict__ w_ih0, const float* __restrict__ w_ihs,
    const float* __restrict__ w_hhs, const float* __restrict__ b_ihs,
    const float* __restrict__ b_hhs, uint32* __restrict__ plane0,
    uint32* __restrict__ plane1, float* __restrict__ outp) {
  const int bid = blockIdx.x;
  const int l = bid >> 5;
  const int idx = bid & 31;
  const int jg = idx >> 1;
  const int bg = idx & 1;
  if (l == 0)      run_layer<0>(x, h0, w_ih0, w_ihs, w_hhs, b_ihs, b_hhs, plane0, plane1, outp, jg, bg);
  else if (l == 1) run_layer<1>(x, h0, w_ih0, w_ihs, w_hhs, b_ihs, b_hhs, plane0, plane1, outp, jg, bg);
  else             run_layer<2>(x, h0, w_ih0, w_ihs, w_hhs, b_ihs, b_hhs, plane0, plane1, outp, jg, bg);
}

// hidden[l][b][j] for l in {0,1} from the last pair-plane slot (exact-ish: hi + lo*2^-12;
// the bit16 tag rides inside lo -> ~2.4e-7 error)
__global__ __launch_bounds__(256) void finals_kernel(const uint32* __restrict__ plane0,
                                                     const uint32* __restrict__ plane1,
                                                     float* __restrict__ outp) {
  int i = blockIdx.x * 256 + threadIdx.x;
  if (i >= 2 * 32 * 512) return;
  int l = i >> 14;
  int r = i & 16383;  // b*512 + j
  const uint32* pl = l ? plane1 : plane0;
  uint32 p = pl[1023 * 32 * 512 + r];
  union { ushort16 u; _Float16 f; } h, lo;
  h.u = (ushort16)(p & 0xFFFFu);
  lo.u = (ushort16)(p >> 16);
  outp[i] = (float)h.f + (float)lo.f * (1.0f / 4096.0f);
}

extern "C" void kernel_launch(void* const* d_in, const int* in_sizes, int n_in,
                              void* d_out, int out_size, void* d_ws, size_t ws_size,
                              hipStream_t stream) {
  const float* x     = (const float*)d_in[0];
  const float* h0    = (const float*)d_in[1];
  const float* w_ih0 = (const float*)d_in[2];
  const float* w_ihs = (const float*)d_in[3];
  const float* w_hhs = (const float*)d_in[4];
  const float* b_ihs = (const float*)d_in[5];
  const float* b_hhs = (const float*)d_in[6];

  uint32* plane0 = (uint32*)d_ws;            // layer-0 outputs, (hi,lo) f16 pairs, 64 MB
  uint32* plane1 = plane0 + PLANE_ELEMS;     // layer-1 outputs, 64 MB

  // tag freshness: planes and out2 must start all-zero every launch
  hipMemsetAsync(plane0, 0, (size_t)2 * PLANE_ELEMS * 4, stream);
  hipMemsetAsync((float*)d_out + 3 * 32 * 512, 0, (size_t)32 * 1024 * 512 * 4, stream);
  rnn_persist<<<96, 256, 0, stream>>>(x, h0, w_ih0, w_ihs, w_hhs, b_ihs, b_hhs,
                                      plane0, plane1, (float*)d_out);
  finals_kernel<<<128, 256, 0, stream>>>(plane0, plane1, (float*)d_out);
}